// Round 5
// baseline (38.860 us; speedup 1.0000x reference)
//
#include <hip/hip_runtime.h>
#include <math.h>

#define NN 384
#define DD 128
#define KCH 16
#define NCHUNK (NN / KCH)   // 24
#define NCLS 10
#define CMAX 64
#define STR 132             // padded LDS row stride (16B-aligned, bank-shift 4/row)
#define EPSF 1e-6f

// K1: B = X G^T, A = B G, prod[i]=|B_i|^2, p2[i]=|A_i|^2, out[i]=+inf
__global__ void __launch_bounds__(128) k_A(const float* __restrict__ X,
                                           const float* __restrict__ G,
                                           float* __restrict__ B,
                                           float* __restrict__ A,
                                           float* __restrict__ prod,
                                           float* __restrict__ p2,
                                           float* __restrict__ out) {
    __shared__ float Xi[DD];
    __shared__ float Bs[DD];
    __shared__ float rp[2], rq[2];
    const int i = blockIdx.x;
    const int t = threadIdx.x;

    if (t < DD / 4) ((float4*)Xi)[t] = ((const float4*)(X + (size_t)i * DD))[t];
    __syncthreads();

    // B[i][t] = sum_d X[i][d] * G[t][d]
    float b = 0.f;
    const float* gr = G + (size_t)t * DD;
#pragma unroll
    for (int d = 0; d < DD; d += 4) {
        float4 g = *(const float4*)(gr + d);
        b = fmaf(g.x, Xi[d + 0], b);
        b = fmaf(g.y, Xi[d + 1], b);
        b = fmaf(g.z, Xi[d + 2], b);
        b = fmaf(g.w, Xi[d + 3], b);
    }
    Bs[t] = b;
    B[(size_t)i * DD + t] = b;
    __syncthreads();

    // A[i][t] = sum_c B[i][c] * G[c][t]   (coalesced G reads)
    float a = 0.f;
#pragma unroll 8
    for (int c = 0; c < DD; ++c)
        a = fmaf(Bs[c], G[(size_t)c * DD + t], a);
    A[(size_t)i * DD + t] = a;

    float pp = b * b, qq = a * a;
#pragma unroll
    for (int off = 32; off > 0; off >>= 1) {
        pp += __shfl_down(pp, off);
        qq += __shfl_down(qq, off);
    }
    if ((t & 63) == 0) { rp[t >> 6] = pp; rq[t >> 6] = qq; }
    __syncthreads();
    if (t == 0) {
        prod[i] = rp[0] + rp[1];
        p2[i]   = rq[0] + rq[1];
        out[i]  = __builtin_inff();
    }
}

// K2: block (chunk kx, class C): local Grams -> margins -> min over chunk k's
//     -> atomicMin(out[i]) for i in class C.
__global__ void __launch_bounds__(256) k_margin(const float* __restrict__ B,
                                                const float* __restrict__ A,
                                                const float* __restrict__ prod,
                                                const float* __restrict__ p2,
                                                const int* __restrict__ y,
                                                float* __restrict__ out) {
    __shared__ float SC[CMAX][STR];      // class rows (B, then A)
    __shared__ float SK[KCH][STR];       // chunk rows (B, then A)
    __shared__ float ccc[CMAX][CMAX];    // csmd class x class
    __shared__ float cck[CMAX][KCH];     // csmd class x chunk
    __shared__ float ick[CMAX][KCH];     // invd class x chunk
    __shared__ float pc[CMAX], qc[CMAX];
    __shared__ float pk[KCH], qk[KCH];
    __shared__ int   yk[KCH];
    __shared__ int   list[CMAX];
    __shared__ int   cnt;

    const int t  = threadIdx.x;
    const int tx = t & 15, ty = t >> 4;
    const int C  = blockIdx.y;
    const int k0 = blockIdx.x * KCH;

    if (t == 0) cnt = 0;
    __syncthreads();
    for (int r = t; r < NN; r += 256) {
        if (y[r] == C) {
            int p = atomicAdd(&cnt, 1);
            if (p < CMAX) {
                list[p] = r;
                pc[p] = prod[r];
                qc[p] = p2[r];
            }
        }
    }
    if (t < KCH) {
        pk[t] = prod[k0 + t];
        qk[t] = p2[k0 + t];
        yk[t] = y[k0 + t];
    }
    __syncthreads();
    const int nc = min(cnt, CMAX);

    // ---- stage B rows
    for (int idx = t; idx < nc * 32; idx += 256) {
        int r = idx >> 5, q = idx & 31;
        *(float4*)&SC[r][q * 4] = ((const float4*)(B + (size_t)list[r] * DD))[q];
    }
    for (int idx = t; idx < KCH * 32; idx += 256) {
        int r = idx >> 5, q = idx & 31;
        *(float4*)&SK[r][q * 4] = ((const float4*)(B + (size_t)(k0 + r) * DD))[q];
    }
    __syncthreads();

    // ---- Gram CC: ccc[i][j] = pc[i]+pc[j]-2*B_i.B_j   (4i x 4j per thread)
    {
        const int i0 = ty * 4;
        if (i0 < nc) {
            float acc[4][4] = {};
#pragma unroll 2
            for (int d = 0; d < DD; d += 4) {
                float4 bi[4], bj[4];
#pragma unroll
                for (int a = 0; a < 4; ++a) bi[a] = *(const float4*)&SC[i0 + a][d];
#pragma unroll
                for (int rj = 0; rj < 4; ++rj) bj[rj] = *(const float4*)&SC[tx + 16 * rj][d];
#pragma unroll
                for (int a = 0; a < 4; ++a)
#pragma unroll
                    for (int rj = 0; rj < 4; ++rj) {
                        acc[a][rj] = fmaf(bi[a].x, bj[rj].x, acc[a][rj]);
                        acc[a][rj] = fmaf(bi[a].y, bj[rj].y, acc[a][rj]);
                        acc[a][rj] = fmaf(bi[a].z, bj[rj].z, acc[a][rj]);
                        acc[a][rj] = fmaf(bi[a].w, bj[rj].w, acc[a][rj]);
                    }
            }
#pragma unroll
            for (int a = 0; a < 4; ++a) {
                const int i = i0 + a;
                if (i < nc)
#pragma unroll
                    for (int rj = 0; rj < 4; ++rj) {
                        const int j = tx + 16 * rj;
                        ccc[i][j] = pc[i] + pc[j] - 2.f * acc[a][rj];
                    }
            }
        }
    }
    // ---- Gram CK: cck[i][k] = pc[i]+pk[k]-2*B_i.B_k   (4i x 1k per thread)
    {
        float acc[4] = {};
#pragma unroll 2
        for (int d = 0; d < DD; d += 4) {
            float4 bk = *(const float4*)&SK[tx][d];
#pragma unroll
            for (int r = 0; r < 4; ++r) {
                float4 bi = *(const float4*)&SC[ty + 16 * r][d];
                acc[r] = fmaf(bi.x, bk.x, acc[r]);
                acc[r] = fmaf(bi.y, bk.y, acc[r]);
                acc[r] = fmaf(bi.z, bk.z, acc[r]);
                acc[r] = fmaf(bi.w, bk.w, acc[r]);
            }
        }
#pragma unroll
        for (int r = 0; r < 4; ++r) {
            const int i = ty + 16 * r;
            if (i < nc) cck[i][tx] = pc[i] + pk[tx] - 2.f * acc[r];
        }
    }
    __syncthreads();

    // ---- restage A rows (overwrite SC/SK), set diag(ccc)=+inf (j==i exclusion)
    for (int idx = t; idx < nc * 32; idx += 256) {
        int r = idx >> 5, q = idx & 31;
        *(float4*)&SC[r][q * 4] = ((const float4*)(A + (size_t)list[r] * DD))[q];
    }
    for (int idx = t; idx < KCH * 32; idx += 256) {
        int r = idx >> 5, q = idx & 31;
        *(float4*)&SK[r][q * 4] = ((const float4*)(A + (size_t)(k0 + r) * DD))[q];
    }
    if (t < nc) ccc[t][t] = __builtin_inff();
    __syncthreads();

    // ---- Gram invd: ick[j][k] = 1/max(2*sqrt(max(qc[j]+qk[k]-2*A_j.A_k, eps)), eps)
    {
        float acc[4] = {};
#pragma unroll 2
        for (int d = 0; d < DD; d += 4) {
            float4 ak = *(const float4*)&SK[tx][d];
#pragma unroll
            for (int r = 0; r < 4; ++r) {
                float4 ai = *(const float4*)&SC[ty + 16 * r][d];
                acc[r] = fmaf(ai.x, ak.x, acc[r]);
                acc[r] = fmaf(ai.y, ak.y, acc[r]);
                acc[r] = fmaf(ai.z, ak.z, acc[r]);
                acc[r] = fmaf(ai.w, ak.w, acc[r]);
            }
        }
#pragma unroll
        for (int r = 0; r < 4; ++r) {
            const int j = ty + 16 * r;
            if (j < nc) {
                float c2 = qc[j] + qk[tx] - 2.f * acc[r];
                ick[j][tx] = 1.f / fmaxf(2.f * sqrtf(fmaxf(c2, EPSF)), EPSF);
            }
        }
    }
    __syncthreads();

    // ---- margins: m(i,k) = max_j relu(cck[i][k]-ccc[i][j]) * ick[j][k];
    //      exclude same-class k; min over the 16 k-lanes; atomicMin into out.
    {
        const bool kex = (yk[tx] == C);
#pragma unroll
        for (int r = 0; r < 4; ++r) {
            const int i = ty + 16 * r;
            float m = 0.f;
            if (i < nc) {
                const float cik = cck[i][tx];
#pragma unroll 4
                for (int j = 0; j < nc; ++j) {
                    float dlt = fmaxf(cik - ccc[i][j], 0.f);
                    m = fmaxf(m, dlt * ick[j][tx]);
                }
            }
            if (kex) m = __builtin_inff();
#pragma unroll
            for (int off = 1; off < 16; off <<= 1)
                m = fminf(m, __shfl_xor(m, off));
            if (tx == 0 && i < nc)
                atomicMin((int*)&out[list[i]], __float_as_int(m));
        }
    }
}

extern "C" void kernel_launch(void* const* d_in, const int* in_sizes, int n_in,
                              void* d_out, int out_size, void* d_ws, size_t ws_size,
                              hipStream_t stream) {
    const float* X = (const float*)d_in[0];
    const float* G = (const float*)d_in[1];
    const int*   y = (const int*)d_in[2];

    float* ws   = (float*)d_ws;
    float* B    = ws;                  // 384*128
    float* A    = B + NN * DD;         // 384*128
    float* prod = A + NN * DD;         // 384
    float* p2   = prod + NN;           // 384
    float* out  = (float*)d_out;

    k_A     <<<dim3(NN), dim3(DD), 0, stream>>>(X, G, B, A, prod, p2, out);
    k_margin<<<dim3(NCHUNK, NCLS), dim3(256), 0, stream>>>(B, A, prod, p2, y, out);
}